// Round 11
// baseline (267.718 us; speedup 1.0000x reference)
//
#include <hip/hip_runtime.h>

#define D 64
#define NB 256      // partition blocks for hist/scatter
#define BSHIFT 8    // bucket = 256 nodes
#define SLOTS 32    // fixed pr slots per node (31 payload + 1 chain/pad)
#define MAXCONT 65536

typedef unsigned int u32;
typedef unsigned short u16;
typedef short bf8v __attribute__((ext_vector_type(8)));
typedef float f4v __attribute__((ext_vector_type(4)));

__device__ __forceinline__ float bf_lo(u32 p) { return __uint_as_float(p << 16); }
__device__ __forceinline__ float bf_hi(u32 p) { return __uint_as_float(p & 0xffff0000u); }
__device__ __forceinline__ u32 bf_rne(float f) {
    u32 u = __float_as_uint(f);
    return (u + 0x7fffu + ((u >> 16) & 1u)) >> 16;
}

// ---------------- cast x to packed bf16 + zero overflow counter ----------------
__global__ void cast_k(const float4* __restrict__ x, uint2* __restrict__ xb, int n4,
                       int* __restrict__ ovf) {
    int i = blockIdx.x * blockDim.x + threadIdx.x;
    if (i == 0) *ovf = 0;
    if (i < n4) {
        float4 v = x[i];
        uint2 o;
        o.x = bf_rne(v.x) | (bf_rne(v.y) << 16);
        o.y = bf_rne(v.z) | (bf_rne(v.w) << 16);
        xb[i] = o;
    }
}

// ---------------- pass A: per-block bucket histogram (LDS atomics only) --------
__global__ __launch_bounds__(256) void hist_k(const int* __restrict__ dst,
                                              int* __restrict__ histT, int E, int chunk,
                                              int nbuck) {
    __shared__ int h[512];
    int t = threadIdx.x;
    for (int b = t; b < nbuck; b += 256) h[b] = 0;
    __syncthreads();
    int start = blockIdx.x * chunk;
    int endi = min(E, start + chunk);
    for (int j = start + t; j < endi; j += 256) atomicAdd(&h[dst[j] >> BSHIFT], 1);
    __syncthreads();
    for (int b = t; b < nbuck; b += 256) histT[b * NB + blockIdx.x] = h[b];
}

// ---------------- generic grid scan (for histT) ----------------
__global__ __launch_bounds__(1024) void gscan1_k(const int* __restrict__ in,
                                                 int* __restrict__ out,
                                                 int* __restrict__ partials, int M) {
    __shared__ int wsum[16];
    int t = threadIdx.x, wave = t >> 6, lane = t & 63;
    int i = blockIdx.x * 1024 + t;
    int v = (i < M) ? in[i] : 0;
    int x = v;
#pragma unroll
    for (int off = 1; off < 64; off <<= 1) {
        int y = __shfl_up(x, off, 64);
        if (lane >= off) x += y;
    }
    if (lane == 63) wsum[wave] = x;
    __syncthreads();
    if (wave == 0) {
        int s = (lane < 16) ? wsum[lane] : 0;
#pragma unroll
        for (int off = 1; off < 16; off <<= 1) {
            int y = __shfl_up(s, off, 64);
            if (lane >= off) s += y;
        }
        if (lane < 16) wsum[lane] = s;
    }
    __syncthreads();
    int woff = (wave > 0) ? wsum[wave - 1] : 0;
    if (i < M) out[i] = x + woff - v;
    if (t == 0) partials[blockIdx.x] = wsum[15];
}

__global__ __launch_bounds__(128) void scan2_k(const int* __restrict__ partials,
                                               int* __restrict__ blockoff,
                                               int* __restrict__ totalp, int nb) {
    __shared__ int s[128];
    int t = threadIdx.x;
    int v = (t < nb) ? partials[t] : 0;
    s[t] = v;
    __syncthreads();
    for (int off = 1; off < 128; off <<= 1) {
        int add = (t >= off) ? s[t - off] : 0;
        __syncthreads();
        s[t] += add;
        __syncthreads();
    }
    blockoff[t] = s[t] - v;
    if (t == nb - 1) *totalp = s[t];
}

__global__ void gadd_k(int* __restrict__ data, const int* __restrict__ blockoff, int M) {
    int i = blockIdx.x * blockDim.x + threadIdx.x;
    if (i < M) data[i] += blockoff[i >> 10];
}

// ---------------- pass B: scatter edges into bucket-sorted segments ----------
__global__ __launch_bounds__(256) void bscat_k(const int* __restrict__ src,
                                               const int* __restrict__ dst,
                                               const int* __restrict__ segT,
                                               int2* __restrict__ pairs, int E, int chunk,
                                               int nbuck) {
    __shared__ int sbase[512];
    __shared__ int rank[512];
    int t = threadIdx.x;
    for (int b = t; b < nbuck; b += 256) {
        sbase[b] = segT[b * NB + blockIdx.x];
        rank[b] = 0;
    }
    __syncthreads();
    int start = blockIdx.x * chunk;
    int endi = min(E, start + chunk);
    for (int j = start + t; j < endi; j += 256) {
        int d = dst[j];
        int b = d >> BSHIFT;
        int pos = sbase[b] + atomicAdd(&rank[b], 1);
        pairs[pos] = make_int2(src[j], d);
    }
}

// ---------------- pass C1: per-node count (LDS) -> cnt + dinv ----------------
__global__ __launch_bounds__(256) void bcount_k(const int2* __restrict__ pairs,
                                                const int* __restrict__ segT,
                                                int* __restrict__ cnt,
                                                float* __restrict__ dinv, int N, int nbuck,
                                                int E) {
    __shared__ int c[1 << BSHIFT];
    int t = threadIdx.x;
    int b = blockIdx.x;
    int base = b << BSHIFT;
    c[t] = 0;
    __syncthreads();
    int s0 = segT[b * NB];
    int s1 = (b + 1 < nbuck) ? segT[(b + 1) * NB] : E;
    for (int j = s0 + t; j < s1; j += 256) atomicAdd(&c[pairs[j].y - base], 1);
    __syncthreads();
    int n = base + t;
    if (n < N) {
        cnt[n] = c[t];
        dinv[n] = rsqrtf((float)c[t] + 1.0f);
    }
}

// ---------------- pass C2: per-bucket fixed-32 fill with overflow chains ------
// node n's slots: pr[32n .. 32n+31]; slot 0 = self, 1..30 = edges/pads,
// slot 31 = pad (n,+0.0) or chain (cont_idx, -0.0). Cont blocks at pr+32N.
__global__ __launch_bounds__(256) void bfill_k(const int2* __restrict__ pairs,
                                               const int* __restrict__ segT,
                                               const int* __restrict__ cnt,
                                               const float* __restrict__ dinv,
                                               int2* __restrict__ pr, int* __restrict__ ovf,
                                               int N, int nbuck, int E) {
    __shared__ int cur[1 << BSHIFT];
    __shared__ int cbase[1 << BSHIFT];
    int t = threadIdx.x;
    int b = blockIdx.x;
    int base = b << BSHIFT;
    int n = base + t;
    int nblk = 0;
    if (n < N) {
        int c = cnt[n];
        float di = dinv[n];
        pr[(size_t)n * SLOTS] = make_int2(n, __float_as_int(di * di));  // self
        nblk = (c > 30) ? (c / 31) : 0;
        int cb = 0;
        if (nblk) cb = atomicAdd(ovf, nblk);
        cbase[t] = cb;
        cur[t] = 1;
        if (nblk == 0) {
            pr[(size_t)n * SLOTS + 31] = make_int2(n, 0);  // +0.0 pad
        } else {
            pr[(size_t)n * SLOTS + 31] = make_int2(cb, (int)0x80000000u);  // chain
            for (int k = 0; k < nblk; ++k) {
                size_t cs = (size_t)N * SLOTS + (size_t)(cb + k) * SLOTS + 31;
                pr[cs] = (k < nblk - 1) ? make_int2(cb + k + 1, (int)0x80000000u)
                                        : make_int2(n, 0);
            }
        }
    }
    __syncthreads();
    int s0 = segT[b * NB];
    int s1 = (b + 1 < nbuck) ? segT[(b + 1) * NB] : E;
    for (int j = s0 + t; j < s1; j += 256) {
        int2 e = pairs[j];
        int local = e.y - base;
        int pos = atomicAdd(&cur[local], 1);
        size_t phys;
        if (pos < 31)
            phys = (size_t)e.y * SLOTS + pos;
        else
            phys = (size_t)N * SLOTS +
                   (size_t)(cbase[local] + (pos - 31) / 31) * SLOTS + (pos - 31) % 31;
        pr[phys] = make_int2(e.x, __float_as_int(dinv[e.x] * dinv[e.y]));
    }
    __syncthreads();
    if (n < N) {
        int total = 31 + 31 * nblk;
        int cb = cbase[t];
        for (int pos = cur[t]; pos < total; ++pos) {
            size_t phys;
            if (pos < 31)
                phys = (size_t)n * SLOTS + pos;
            else
                phys = (size_t)N * SLOTS + (size_t)(cb + (pos - 31) / 31) * SLOTS +
                       (pos - 31) % 31;
            pr[phys] = make_int2(n, 0);  // +0.0 pad
        }
    }
}

// ---------------- dense GEMM via MFMA 16x16x32 bf16: hout = hb @ W ----------------
__global__ __launch_bounds__(256) void gemm_k(const u32* __restrict__ hb,
                                              const float* __restrict__ W,
                                              u16* __restrict__ hout, int N) {
    int t = threadIdx.x;
    int lane = t & 63;
    int m = lane & 15;
    int quad = lane >> 4;
    bf8v Bf[2][4];
#pragma unroll
    for (int kc = 0; kc < 2; ++kc)
#pragma unroll
        for (int nb = 0; nb < 4; ++nb)
#pragma unroll
            for (int j = 0; j < 8; ++j)
                Bf[kc][nb][j] = (short)bf_rne(W[(32 * kc + 8 * quad + j) * D + m + 16 * nb]);
    int ngroups = (N + 15) >> 4;
    int g = blockIdx.x * 4 + (t >> 6);
    int stride = gridDim.x * 4;
    for (; g < ngroups; g += stride) {
        int base = g * 16;
        int r0 = base + m;
        if (r0 >= N) r0 = N - 1;
        f4v acc[4] = {{0.f, 0.f, 0.f, 0.f},
                      {0.f, 0.f, 0.f, 0.f},
                      {0.f, 0.f, 0.f, 0.f},
                      {0.f, 0.f, 0.f, 0.f}};
#pragma unroll
        for (int kc = 0; kc < 2; ++kc) {
            bf8v Af = *(const bf8v*)(hb + (size_t)r0 * 32 + kc * 16 + quad * 4);
#pragma unroll
            for (int nb = 0; nb < 4; ++nb)
                acc[nb] = __builtin_amdgcn_mfma_f32_16x16x32_bf16(Af, Bf[kc][nb], acc[nb],
                                                                  0, 0, 0);
        }
#pragma unroll
        for (int nb = 0; nb < 4; ++nb)
#pragma unroll
            for (int r = 0; r < 4; ++r) {
                int rowi = base + quad * 4 + r;
                if (rowi < N)
                    hout[(size_t)rowi * D + nb * 16 + m] = (u16)bf_rne(acc[nb][r]);
            }
    }
}

// ---------------- lean gather: out = relu( A_norm @ h + b ) ----------------
// wave per node, fixed 32 slots at pr[32i]. 8 lanes per gathered row:
// q = lane>>3 handles slots {2q,2q+1,16+2q,16+2q+1}; p = lane&7 picks 8 packed
// bf16 features (uint4). __launch_bounds__(256,8) pins VGPR<=64 -> 8 waves/SIMD
// (R6 post-mortem: crossing 64 VGPRs halves the resident-wave pool).
__global__ __launch_bounds__(256, 8) void agg_k(const uint4* __restrict__ h4,
                                                const int2* __restrict__ pr,
                                                const float* __restrict__ b,
                                                float* __restrict__ out_f32,
                                                u16* __restrict__ out_b16, int N) {
    int t = threadIdx.x;
    int lane = t & 63;
    int p = lane & 7;
    int q = lane >> 3;
    float4 ba = *(const float4*)(b + 8 * p);
    float4 bb = *(const float4*)(b + 8 * p + 4);
    int wid = blockIdx.x * 4 + (t >> 6);
    int nw = gridDim.x * 4;
    for (int i = wid; i < N; i += nw) {
        float v0 = 0.f, v1 = 0.f, v2 = 0.f, v3 = 0.f;
        float v4 = 0.f, v5 = 0.f, v6 = 0.f, v7 = 0.f;
        int4 el1;
        const int2* bp = pr + (size_t)i * SLOTS;
        for (;;) {
            int4 el0 = ((const int4*)bp)[q];      // slots 2q, 2q+1
            el1 = ((const int4*)bp)[8 + q];       // slots 16+2q, 16+2q+1
            uint4 g0 = h4[(size_t)(u32)el0.x * 8 + p];
            uint4 g1 = h4[(size_t)(u32)el0.z * 8 + p];
            uint4 g2 = h4[(size_t)(u32)el1.x * 8 + p];
            uint4 g3 = h4[(size_t)(u32)el1.z * 8 + p];
            float w0 = __int_as_float(el0.y);
            float w1 = __int_as_float(el0.w);
            float w2 = __int_as_float(el1.y);
            float w3 = __int_as_float(el1.w);
            v0 = fmaf(bf_lo(g0.x), w0, v0); v1 = fmaf(bf_hi(g0.x), w0, v1);
            v2 = fmaf(bf_lo(g0.y), w0, v2); v3 = fmaf(bf_hi(g0.y), w0, v3);
            v4 = fmaf(bf_lo(g0.z), w0, v4); v5 = fmaf(bf_hi(g0.z), w0, v5);
            v6 = fmaf(bf_lo(g0.w), w0, v6); v7 = fmaf(bf_hi(g0.w), w0, v7);
            v0 = fmaf(bf_lo(g1.x), w1, v0); v1 = fmaf(bf_hi(g1.x), w1, v1);
            v2 = fmaf(bf_lo(g1.y), w1, v2); v3 = fmaf(bf_hi(g1.y), w1, v3);
            v4 = fmaf(bf_lo(g1.z), w1, v4); v5 = fmaf(bf_hi(g1.z), w1, v5);
            v6 = fmaf(bf_lo(g1.w), w1, v6); v7 = fmaf(bf_hi(g1.w), w1, v7);
            v0 = fmaf(bf_lo(g2.x), w2, v0); v1 = fmaf(bf_hi(g2.x), w2, v1);
            v2 = fmaf(bf_lo(g2.y), w2, v2); v3 = fmaf(bf_hi(g2.y), w2, v3);
            v4 = fmaf(bf_lo(g2.z), w2, v4); v5 = fmaf(bf_hi(g2.z), w2, v5);
            v6 = fmaf(bf_lo(g2.w), w2, v6); v7 = fmaf(bf_hi(g2.w), w2, v7);
            v0 = fmaf(bf_lo(g3.x), w3, v0); v1 = fmaf(bf_hi(g3.x), w3, v1);
            v2 = fmaf(bf_lo(g3.y), w3, v2); v3 = fmaf(bf_hi(g3.y), w3, v3);
            v4 = fmaf(bf_lo(g3.z), w3, v4); v5 = fmaf(bf_hi(g3.z), w3, v5);
            v6 = fmaf(bf_lo(g3.w), w3, v6); v7 = fmaf(bf_hi(g3.w), w3, v7);
            int flag = __shfl(el1.w, 63, 64);  // slot 31 weight bits
            if (flag >= 0) break;              // pad (+0.0) -> done
            int c = __shfl(el1.z, 63, 64);     // chain to cont block
            bp = pr + (size_t)N * SLOTS + (size_t)c * SLOTS;
        }
        v0 += __shfl_xor(v0, 8, 64);  v1 += __shfl_xor(v1, 8, 64);
        v2 += __shfl_xor(v2, 8, 64);  v3 += __shfl_xor(v3, 8, 64);
        v4 += __shfl_xor(v4, 8, 64);  v5 += __shfl_xor(v5, 8, 64);
        v6 += __shfl_xor(v6, 8, 64);  v7 += __shfl_xor(v7, 8, 64);
        v0 += __shfl_xor(v0, 16, 64); v1 += __shfl_xor(v1, 16, 64);
        v2 += __shfl_xor(v2, 16, 64); v3 += __shfl_xor(v3, 16, 64);
        v4 += __shfl_xor(v4, 16, 64); v5 += __shfl_xor(v5, 16, 64);
        v6 += __shfl_xor(v6, 16, 64); v7 += __shfl_xor(v7, 16, 64);
        v0 += __shfl_xor(v0, 32, 64); v1 += __shfl_xor(v1, 32, 64);
        v2 += __shfl_xor(v2, 32, 64); v3 += __shfl_xor(v3, 32, 64);
        v4 += __shfl_xor(v4, 32, 64); v5 += __shfl_xor(v5, 32, 64);
        v6 += __shfl_xor(v6, 32, 64); v7 += __shfl_xor(v7, 32, 64);
        v0 = fmaxf(v0 + ba.x, 0.f); v1 = fmaxf(v1 + ba.y, 0.f);
        v2 = fmaxf(v2 + ba.z, 0.f); v3 = fmaxf(v3 + ba.w, 0.f);
        v4 = fmaxf(v4 + bb.x, 0.f); v5 = fmaxf(v5 + bb.y, 0.f);
        v6 = fmaxf(v6 + bb.z, 0.f); v7 = fmaxf(v7 + bb.w, 0.f);
        if (q == 0) {
            if (out_b16) {
                uint4 o;
                o.x = bf_rne(v0) | (bf_rne(v1) << 16);
                o.y = bf_rne(v2) | (bf_rne(v3) << 16);
                o.z = bf_rne(v4) | (bf_rne(v5) << 16);
                o.w = bf_rne(v6) | (bf_rne(v7) << 16);
                *(uint4*)(out_b16 + (size_t)i * D + 8 * p) = o;
            } else {
                float* dst = out_f32 + (size_t)i * D + 8 * p;
                *(float4*)dst = make_float4(v0, v1, v2, v3);
                *(float4*)(dst + 4) = make_float4(v4, v5, v6, v7);
            }
        }
    }
}

// ---------------- launch ----------------

extern "C" void kernel_launch(void* const* d_in, const int* in_sizes, int n_in,
                              void* d_out, int out_size, void* d_ws, size_t ws_size,
                              hipStream_t stream) {
    const float* x  = (const float*)d_in[0];
    const int*   ei = (const int*)d_in[1];
    const float* W1 = (const float*)d_in[2];
    const float* b1 = (const float*)d_in[3];
    const float* W2 = (const float*)d_in[4];
    const float* b2 = (const float*)d_in[5];
    float* out = (float*)d_out;

    int N = in_sizes[0] / D;
    int E = in_sizes[1] / 2;
    const int* src = ei;
    const int* dst = ei + E;

    int nbuck = (N + (1 << BSHIFT) - 1) >> BSHIFT;  // 391
    int chunk = (E + NB - 1) / NB;
    int M = nbuck * NB;

    char* ws = (char*)d_ws;
    size_t off = 0;
    auto align256 = [](size_t v) { return (v + 255) & ~(size_t)255; };
    int* cnt = (int*)(ws + off);       off += align256((size_t)N * 4);
    float* dinv = (float*)(ws + off);  off += align256((size_t)N * 4);
    int* partials2 = (int*)(ws + off); off += 512;
    int* blockoff2 = (int*)(ws + off); off += 512;
    int* scratch = (int*)(ws + off);   off += 256;
    int* ovf = (int*)(ws + off);       off += 256;
    int* histT = (int*)(ws + off);     off += align256((size_t)M * 4);
    int2* pairs = (int2*)(ws + off);   off += align256((size_t)E * 8);
    int2* pr = (int2*)(ws + off);      off += align256(((size_t)N + MAXCONT) * SLOTS * 8);
    u32* xb = (u32*)(ws + off);        off += align256((size_t)N * D * 2);
    u16* h = (u16*)(ws + off);         off += align256((size_t)N * D * 2);
    u16* buf16 = (u16*)(ws + off);     off += align256((size_t)N * D * 2);

    dim3 b256(256);
    int nbG = (M + 1023) / 1024;  // hist-scan blocks (98)

    cast_k<<<(N * D / 4 + 255) / 256, b256, 0, stream>>>((const float4*)x, (uint2*)xb,
                                                         N * D / 4, ovf);
    hist_k<<<NB, b256, 0, stream>>>(dst, histT, E, chunk, nbuck);
    gscan1_k<<<nbG, 1024, 0, stream>>>(histT, histT, partials2, M);
    scan2_k<<<1, 128, 0, stream>>>(partials2, blockoff2, scratch, nbG);
    gadd_k<<<(M + 255) / 256, b256, 0, stream>>>(histT, blockoff2, M);
    bscat_k<<<NB, b256, 0, stream>>>(src, dst, histT, pairs, E, chunk, nbuck);
    bcount_k<<<nbuck, b256, 0, stream>>>(pairs, histT, cnt, dinv, N, nbuck, E);
    bfill_k<<<nbuck, b256, 0, stream>>>(pairs, histT, cnt, dinv, pr, ovf, N, nbuck, E);

    int ngroups = (N + 15) / 16;
    int gemm_blocks = (ngroups + 3) / 4;

    // layer 1: h = x @ W1 ; buf16 = bf16(relu(agg(h) + b1))
    gemm_k<<<gemm_blocks, b256, 0, stream>>>(xb, W1, h, N);
    agg_k<<<2560, b256, 0, stream>>>((const uint4*)h, pr, b1, nullptr, buf16, N);
    // layer 2: h = buf16 @ W2 ; out = relu(agg(h) + b2)
    gemm_k<<<gemm_blocks, b256, 0, stream>>>((const u32*)buf16, W2, h, N);
    agg_k<<<2560, b256, 0, stream>>>((const uint4*)h, pr, b2, out, nullptr, N);
}

// Round 12
// 224.135 us; speedup vs baseline: 1.1945x; 1.1945x over previous
//
#include <hip/hip_runtime.h>

#define D 64
#define NB 256      // partition blocks for hist/scatter
#define BSHIFT 8    // bucket = 256 nodes
#define SLOTS 32    // fixed pr slots per node (31 payload + 1 chain/pad)
#define MAXCONT 65536

typedef unsigned int u32;
typedef unsigned short u16;
typedef short bf8v __attribute__((ext_vector_type(8)));
typedef float f4v __attribute__((ext_vector_type(4)));

__device__ __forceinline__ float bf_lo(u32 p) { return __uint_as_float(p << 16); }
__device__ __forceinline__ float bf_hi(u32 p) { return __uint_as_float(p & 0xffff0000u); }
__device__ __forceinline__ u32 bf_rne(float f) {
    u32 u = __float_as_uint(f);
    return (u + 0x7fffu + ((u >> 16) & 1u)) >> 16;
}

// ---------------- pass A: per-block bucket histogram (LDS atomics only) --------
__global__ __launch_bounds__(256) void hist_k(const int* __restrict__ dst,
                                              int* __restrict__ histT, int E, int chunk,
                                              int nbuck) {
    __shared__ int h[512];
    int t = threadIdx.x;
    for (int b = t; b < nbuck; b += 256) h[b] = 0;
    __syncthreads();
    int start = blockIdx.x * chunk;
    int endi = min(E, start + chunk);
    for (int j = start + t; j < endi; j += 256) atomicAdd(&h[dst[j] >> BSHIFT], 1);
    __syncthreads();
    for (int b = t; b < nbuck; b += 256) histT[b * NB + blockIdx.x] = h[b];
}

// ---------------- generic grid scan (for histT) ----------------
__global__ __launch_bounds__(1024) void gscan1_k(const int* __restrict__ in,
                                                 int* __restrict__ out,
                                                 int* __restrict__ partials, int M) {
    __shared__ int wsum[16];
    int t = threadIdx.x, wave = t >> 6, lane = t & 63;
    int i = blockIdx.x * 1024 + t;
    int v = (i < M) ? in[i] : 0;
    int x = v;
#pragma unroll
    for (int off = 1; off < 64; off <<= 1) {
        int y = __shfl_up(x, off, 64);
        if (lane >= off) x += y;
    }
    if (lane == 63) wsum[wave] = x;
    __syncthreads();
    if (wave == 0) {
        int s = (lane < 16) ? wsum[lane] : 0;
#pragma unroll
        for (int off = 1; off < 16; off <<= 1) {
            int y = __shfl_up(s, off, 64);
            if (lane >= off) s += y;
        }
        if (lane < 16) wsum[lane] = s;
    }
    __syncthreads();
    int woff = (wave > 0) ? wsum[wave - 1] : 0;
    if (i < M) out[i] = x + woff - v;
    if (t == 0) partials[blockIdx.x] = wsum[15];
}

__global__ __launch_bounds__(128) void scan2_k(const int* __restrict__ partials,
                                               int* __restrict__ blockoff,
                                               int* __restrict__ totalp, int nb) {
    __shared__ int s[128];
    int t = threadIdx.x;
    int v = (t < nb) ? partials[t] : 0;
    s[t] = v;
    __syncthreads();
    for (int off = 1; off < 128; off <<= 1) {
        int add = (t >= off) ? s[t - off] : 0;
        __syncthreads();
        s[t] += add;
        __syncthreads();
    }
    blockoff[t] = s[t] - v;
    if (t == nb - 1) *totalp = s[t];
}

__global__ void gadd_k(int* __restrict__ data, const int* __restrict__ blockoff, int M) {
    int i = blockIdx.x * blockDim.x + threadIdx.x;
    if (i < M) data[i] += blockoff[i >> 10];
}

// ---------------- pass B: scatter edges into bucket-sorted segments ----------
__global__ __launch_bounds__(256) void bscat_k(const int* __restrict__ src,
                                               const int* __restrict__ dst,
                                               const int* __restrict__ segT,
                                               int2* __restrict__ pairs, int E, int chunk,
                                               int nbuck) {
    __shared__ int sbase[512];
    __shared__ int rank[512];
    int t = threadIdx.x;
    for (int b = t; b < nbuck; b += 256) {
        sbase[b] = segT[b * NB + blockIdx.x];
        rank[b] = 0;
    }
    __syncthreads();
    int start = blockIdx.x * chunk;
    int endi = min(E, start + chunk);
    for (int j = start + t; j < endi; j += 256) {
        int d = dst[j];
        int b = d >> BSHIFT;
        int pos = sbase[b] + atomicAdd(&rank[b], 1);
        pairs[pos] = make_int2(src[j], d);
    }
}

// ---------------- pass C1: per-node count (LDS) -> cnt + dinv; zero ovf -------
__global__ __launch_bounds__(256) void bcount_k(const int2* __restrict__ pairs,
                                                const int* __restrict__ segT,
                                                int* __restrict__ cnt,
                                                float* __restrict__ dinv,
                                                int* __restrict__ ovf, int N, int nbuck,
                                                int E) {
    __shared__ int c[1 << BSHIFT];
    int t = threadIdx.x;
    int b = blockIdx.x;
    int base = b << BSHIFT;
    if (b == 0 && t == 0) *ovf = 0;
    c[t] = 0;
    __syncthreads();
    int s0 = segT[b * NB];
    int s1 = (b + 1 < nbuck) ? segT[(b + 1) * NB] : E;
    for (int j = s0 + t; j < s1; j += 256) atomicAdd(&c[pairs[j].y - base], 1);
    __syncthreads();
    int n = base + t;
    if (n < N) {
        cnt[n] = c[t];
        dinv[n] = rsqrtf((float)c[t] + 1.0f);
    }
}

// ---------------- pass C2: per-bucket fixed-32 fill with overflow chains ------
// node n's slots: pr[32n .. 32n+31]; slot 0 = self, 1..30 = edges/pads,
// slot 31 = pad (n,+0.0) or chain (cont_idx, -0.0). Cont blocks at pr+32N.
__global__ __launch_bounds__(256) void bfill_k(const int2* __restrict__ pairs,
                                               const int* __restrict__ segT,
                                               const int* __restrict__ cnt,
                                               const float* __restrict__ dinv,
                                               int2* __restrict__ pr, int* __restrict__ ovf,
                                               int N, int nbuck, int E) {
    __shared__ int cur[1 << BSHIFT];
    __shared__ int cbase[1 << BSHIFT];
    int t = threadIdx.x;
    int b = blockIdx.x;
    int base = b << BSHIFT;
    int n = base + t;
    int nblk = 0;
    if (n < N) {
        int c = cnt[n];
        float di = dinv[n];
        pr[(size_t)n * SLOTS] = make_int2(n, __float_as_int(di * di));  // self
        nblk = (c > 30) ? (c / 31) : 0;
        int cb = 0;
        if (nblk) cb = atomicAdd(ovf, nblk);
        cbase[t] = cb;
        cur[t] = 1;
        if (nblk == 0) {
            pr[(size_t)n * SLOTS + 31] = make_int2(n, 0);  // +0.0 pad
        } else {
            pr[(size_t)n * SLOTS + 31] = make_int2(cb, (int)0x80000000u);  // chain
            for (int k = 0; k < nblk; ++k) {
                size_t cs = (size_t)N * SLOTS + (size_t)(cb + k) * SLOTS + 31;
                pr[cs] = (k < nblk - 1) ? make_int2(cb + k + 1, (int)0x80000000u)
                                        : make_int2(n, 0);
            }
        }
    }
    __syncthreads();
    int s0 = segT[b * NB];
    int s1 = (b + 1 < nbuck) ? segT[(b + 1) * NB] : E;
    for (int j = s0 + t; j < s1; j += 256) {
        int2 e = pairs[j];
        int local = e.y - base;
        int pos = atomicAdd(&cur[local], 1);
        size_t phys;
        if (pos < 31)
            phys = (size_t)e.y * SLOTS + pos;
        else
            phys = (size_t)N * SLOTS +
                   (size_t)(cbase[local] + (pos - 31) / 31) * SLOTS + (pos - 31) % 31;
        pr[phys] = make_int2(e.x, __float_as_int(dinv[e.x] * dinv[e.y]));
    }
    __syncthreads();
    if (n < N) {
        int total = 31 + 31 * nblk;
        int cb = cbase[t];
        for (int pos = cur[t]; pos < total; ++pos) {
            size_t phys;
            if (pos < 31)
                phys = (size_t)n * SLOTS + pos;
            else
                phys = (size_t)N * SLOTS + (size_t)(cb + (pos - 31) / 31) * SLOTS +
                       (pos - 31) % 31;
            pr[phys] = make_int2(n, 0);  // +0.0 pad
        }
    }
}

// ---------------- dense GEMM via MFMA 16x16x32 bf16: hout = in @ W ------------
// B from W (f32 -> bf16). Two input paths: bf16-packed (layer 2) or raw f32
// (layer 1, fuses the x cast — saves the cast kernel + xb round-trip).

__device__ __forceinline__ void gemm_body(bf8v Af0, bf8v Af1, const bf8v Bf[2][4],
                                          u16* __restrict__ hout, int base, int m,
                                          int quad, int N) {
    f4v acc[4] = {{0.f, 0.f, 0.f, 0.f},
                  {0.f, 0.f, 0.f, 0.f},
                  {0.f, 0.f, 0.f, 0.f},
                  {0.f, 0.f, 0.f, 0.f}};
#pragma unroll
    for (int nb = 0; nb < 4; ++nb)
        acc[nb] = __builtin_amdgcn_mfma_f32_16x16x32_bf16(Af0, Bf[0][nb], acc[nb], 0, 0, 0);
#pragma unroll
    for (int nb = 0; nb < 4; ++nb)
        acc[nb] = __builtin_amdgcn_mfma_f32_16x16x32_bf16(Af1, Bf[1][nb], acc[nb], 0, 0, 0);
#pragma unroll
    for (int nb = 0; nb < 4; ++nb)
#pragma unroll
        for (int r = 0; r < 4; ++r) {
            int rowi = base + quad * 4 + r;
            if (rowi < N) hout[(size_t)rowi * D + nb * 16 + m] = (u16)bf_rne(acc[nb][r]);
        }
}

__device__ __forceinline__ void load_B(const float* __restrict__ W, bf8v Bf[2][4], int m,
                                       int quad) {
#pragma unroll
    for (int kc = 0; kc < 2; ++kc)
#pragma unroll
        for (int nb = 0; nb < 4; ++nb)
#pragma unroll
            for (int j = 0; j < 8; ++j)
                Bf[kc][nb][j] = (short)bf_rne(W[(32 * kc + 8 * quad + j) * D + m + 16 * nb]);
}

__global__ __launch_bounds__(256) void gemm_k(const u32* __restrict__ hb,
                                              const float* __restrict__ W,
                                              u16* __restrict__ hout, int N) {
    int t = threadIdx.x;
    int lane = t & 63;
    int m = lane & 15;
    int quad = lane >> 4;
    bf8v Bf[2][4];
    load_B(W, Bf, m, quad);
    int ngroups = (N + 15) >> 4;
    int g = blockIdx.x * 4 + (t >> 6);
    int stride = gridDim.x * 4;
    for (; g < ngroups; g += stride) {
        int base = g * 16;
        int r0 = base + m;
        if (r0 >= N) r0 = N - 1;
        bf8v Af0 = *(const bf8v*)(hb + (size_t)r0 * 32 + quad * 4);
        bf8v Af1 = *(const bf8v*)(hb + (size_t)r0 * 32 + 16 + quad * 4);
        gemm_body(Af0, Af1, Bf, hout, base, m, quad, N);
    }
}

__global__ __launch_bounds__(256) void gemm_f32_k(const float* __restrict__ xf,
                                                  const float* __restrict__ W,
                                                  u16* __restrict__ hout, int N) {
    int t = threadIdx.x;
    int lane = t & 63;
    int m = lane & 15;
    int quad = lane >> 4;
    bf8v Bf[2][4];
    load_B(W, Bf, m, quad);
    int ngroups = (N + 15) >> 4;
    int g = blockIdx.x * 4 + (t >> 6);
    int stride = gridDim.x * 4;
    for (; g < ngroups; g += stride) {
        int base = g * 16;
        int r0 = base + m;
        if (r0 >= N) r0 = N - 1;
        const float* rp = xf + (size_t)r0 * D;
        float4 a0 = *(const float4*)(rp + quad * 8);
        float4 a1 = *(const float4*)(rp + quad * 8 + 4);
        float4 a2 = *(const float4*)(rp + 32 + quad * 8);
        float4 a3 = *(const float4*)(rp + 32 + quad * 8 + 4);
        bf8v Af0, Af1;
        Af0[0] = (short)bf_rne(a0.x); Af0[1] = (short)bf_rne(a0.y);
        Af0[2] = (short)bf_rne(a0.z); Af0[3] = (short)bf_rne(a0.w);
        Af0[4] = (short)bf_rne(a1.x); Af0[5] = (short)bf_rne(a1.y);
        Af0[6] = (short)bf_rne(a1.z); Af0[7] = (short)bf_rne(a1.w);
        Af1[0] = (short)bf_rne(a2.x); Af1[1] = (short)bf_rne(a2.y);
        Af1[2] = (short)bf_rne(a2.z); Af1[3] = (short)bf_rne(a2.w);
        Af1[4] = (short)bf_rne(a3.x); Af1[5] = (short)bf_rne(a3.y);
        Af1[6] = (short)bf_rne(a3.z); Af1[7] = (short)bf_rne(a3.w);
        gemm_body(Af0, Af1, Bf, hout, base, m, quad, N);
    }
}

// ---------------- lean gather: out = relu( A_norm @ h + b ) ----------------
// wave per node, fixed 32 slots at pr[32i]. 8 lanes per gathered row:
// q = lane>>3 handles slots {2q,2q+1,16+2q,16+2q+1}; p = lane&7 picks 8 packed
// bf16 features (uint4). Natural VGPR allocation (=64) is the measured optimum:
// forcing 8 waves/EU pins VGPR to 32 and serializes the gather batch (R11).
__global__ __launch_bounds__(256) void agg_k(const uint4* __restrict__ h4,
                                             const int2* __restrict__ pr,
                                             const float* __restrict__ b,
                                             float* __restrict__ out_f32,
                                             u16* __restrict__ out_b16, int N) {
    int t = threadIdx.x;
    int lane = t & 63;
    int p = lane & 7;
    int q = lane >> 3;
    float4 ba = *(const float4*)(b + 8 * p);
    float4 bb = *(const float4*)(b + 8 * p + 4);
    int wid = blockIdx.x * 4 + (t >> 6);
    int nw = gridDim.x * 4;
    for (int i = wid; i < N; i += nw) {
        float v0 = 0.f, v1 = 0.f, v2 = 0.f, v3 = 0.f;
        float v4 = 0.f, v5 = 0.f, v6 = 0.f, v7 = 0.f;
        int4 el1;
        const int2* bp = pr + (size_t)i * SLOTS;
        for (;;) {
            int4 el0 = ((const int4*)bp)[q];      // slots 2q, 2q+1
            el1 = ((const int4*)bp)[8 + q];       // slots 16+2q, 16+2q+1
            uint4 g0 = h4[(size_t)(u32)el0.x * 8 + p];
            uint4 g1 = h4[(size_t)(u32)el0.z * 8 + p];
            uint4 g2 = h4[(size_t)(u32)el1.x * 8 + p];
            uint4 g3 = h4[(size_t)(u32)el1.z * 8 + p];
            float w0 = __int_as_float(el0.y);
            float w1 = __int_as_float(el0.w);
            float w2 = __int_as_float(el1.y);
            float w3 = __int_as_float(el1.w);
            v0 = fmaf(bf_lo(g0.x), w0, v0); v1 = fmaf(bf_hi(g0.x), w0, v1);
            v2 = fmaf(bf_lo(g0.y), w0, v2); v3 = fmaf(bf_hi(g0.y), w0, v3);
            v4 = fmaf(bf_lo(g0.z), w0, v4); v5 = fmaf(bf_hi(g0.z), w0, v5);
            v6 = fmaf(bf_lo(g0.w), w0, v6); v7 = fmaf(bf_hi(g0.w), w0, v7);
            v0 = fmaf(bf_lo(g1.x), w1, v0); v1 = fmaf(bf_hi(g1.x), w1, v1);
            v2 = fmaf(bf_lo(g1.y), w1, v2); v3 = fmaf(bf_hi(g1.y), w1, v3);
            v4 = fmaf(bf_lo(g1.z), w1, v4); v5 = fmaf(bf_hi(g1.z), w1, v5);
            v6 = fmaf(bf_lo(g1.w), w1, v6); v7 = fmaf(bf_hi(g1.w), w1, v7);
            v0 = fmaf(bf_lo(g2.x), w2, v0); v1 = fmaf(bf_hi(g2.x), w2, v1);
            v2 = fmaf(bf_lo(g2.y), w2, v2); v3 = fmaf(bf_hi(g2.y), w2, v3);
            v4 = fmaf(bf_lo(g2.z), w2, v4); v5 = fmaf(bf_hi(g2.z), w2, v5);
            v6 = fmaf(bf_lo(g2.w), w2, v6); v7 = fmaf(bf_hi(g2.w), w2, v7);
            v0 = fmaf(bf_lo(g3.x), w3, v0); v1 = fmaf(bf_hi(g3.x), w3, v1);
            v2 = fmaf(bf_lo(g3.y), w3, v2); v3 = fmaf(bf_hi(g3.y), w3, v3);
            v4 = fmaf(bf_lo(g3.z), w3, v4); v5 = fmaf(bf_hi(g3.z), w3, v5);
            v6 = fmaf(bf_lo(g3.w), w3, v6); v7 = fmaf(bf_hi(g3.w), w3, v7);
            int flag = __shfl(el1.w, 63, 64);  // slot 31 weight bits
            if (flag >= 0) break;              // pad (+0.0) -> done
            int c = __shfl(el1.z, 63, 64);     // chain to cont block
            bp = pr + (size_t)N * SLOTS + (size_t)c * SLOTS;
        }
        v0 += __shfl_xor(v0, 8, 64);  v1 += __shfl_xor(v1, 8, 64);
        v2 += __shfl_xor(v2, 8, 64);  v3 += __shfl_xor(v3, 8, 64);
        v4 += __shfl_xor(v4, 8, 64);  v5 += __shfl_xor(v5, 8, 64);
        v6 += __shfl_xor(v6, 8, 64);  v7 += __shfl_xor(v7, 8, 64);
        v0 += __shfl_xor(v0, 16, 64); v1 += __shfl_xor(v1, 16, 64);
        v2 += __shfl_xor(v2, 16, 64); v3 += __shfl_xor(v3, 16, 64);
        v4 += __shfl_xor(v4, 16, 64); v5 += __shfl_xor(v5, 16, 64);
        v6 += __shfl_xor(v6, 16, 64); v7 += __shfl_xor(v7, 16, 64);
        v0 += __shfl_xor(v0, 32, 64); v1 += __shfl_xor(v1, 32, 64);
        v2 += __shfl_xor(v2, 32, 64); v3 += __shfl_xor(v3, 32, 64);
        v4 += __shfl_xor(v4, 32, 64); v5 += __shfl_xor(v5, 32, 64);
        v6 += __shfl_xor(v6, 32, 64); v7 += __shfl_xor(v7, 32, 64);
        v0 = fmaxf(v0 + ba.x, 0.f); v1 = fmaxf(v1 + ba.y, 0.f);
        v2 = fmaxf(v2 + ba.z, 0.f); v3 = fmaxf(v3 + ba.w, 0.f);
        v4 = fmaxf(v4 + bb.x, 0.f); v5 = fmaxf(v5 + bb.y, 0.f);
        v6 = fmaxf(v6 + bb.z, 0.f); v7 = fmaxf(v7 + bb.w, 0.f);
        if (q == 0) {
            if (out_b16) {
                uint4 o;
                o.x = bf_rne(v0) | (bf_rne(v1) << 16);
                o.y = bf_rne(v2) | (bf_rne(v3) << 16);
                o.z = bf_rne(v4) | (bf_rne(v5) << 16);
                o.w = bf_rne(v6) | (bf_rne(v7) << 16);
                *(uint4*)(out_b16 + (size_t)i * D + 8 * p) = o;
            } else {
                float* dst = out_f32 + (size_t)i * D + 8 * p;
                *(float4*)dst = make_float4(v0, v1, v2, v3);
                *(float4*)(dst + 4) = make_float4(v4, v5, v6, v7);
            }
        }
    }
}

// ---------------- launch ----------------

extern "C" void kernel_launch(void* const* d_in, const int* in_sizes, int n_in,
                              void* d_out, int out_size, void* d_ws, size_t ws_size,
                              hipStream_t stream) {
    const float* x  = (const float*)d_in[0];
    const int*   ei = (const int*)d_in[1];
    const float* W1 = (const float*)d_in[2];
    const float* b1 = (const float*)d_in[3];
    const float* W2 = (const float*)d_in[4];
    const float* b2 = (const float*)d_in[5];
    float* out = (float*)d_out;

    int N = in_sizes[0] / D;
    int E = in_sizes[1] / 2;
    const int* src = ei;
    const int* dst = ei + E;

    int nbuck = (N + (1 << BSHIFT) - 1) >> BSHIFT;  // 391
    int chunk = (E + NB - 1) / NB;
    int M = nbuck * NB;

    char* ws = (char*)d_ws;
    size_t off = 0;
    auto align256 = [](size_t v) { return (v + 255) & ~(size_t)255; };
    int* cnt = (int*)(ws + off);       off += align256((size_t)N * 4);
    float* dinv = (float*)(ws + off);  off += align256((size_t)N * 4);
    int* partials2 = (int*)(ws + off); off += 512;
    int* blockoff2 = (int*)(ws + off); off += 512;
    int* scratch = (int*)(ws + off);   off += 256;
    int* ovf = (int*)(ws + off);       off += 256;
    int* histT = (int*)(ws + off);     off += align256((size_t)M * 4);
    int2* pairs = (int2*)(ws + off);   off += align256((size_t)E * 8);
    int2* pr = (int2*)(ws + off);      off += align256(((size_t)N + MAXCONT) * SLOTS * 8);
    u16* h = (u16*)(ws + off);         off += align256((size_t)N * D * 2);
    u16* buf16 = (u16*)(ws + off);     off += align256((size_t)N * D * 2);

    dim3 b256(256);
    int nbG = (M + 1023) / 1024;  // hist-scan blocks (98)

    hist_k<<<NB, b256, 0, stream>>>(dst, histT, E, chunk, nbuck);
    gscan1_k<<<nbG, 1024, 0, stream>>>(histT, histT, partials2, M);
    scan2_k<<<1, 128, 0, stream>>>(partials2, blockoff2, scratch, nbG);
    gadd_k<<<(M + 255) / 256, b256, 0, stream>>>(histT, blockoff2, M);
    bscat_k<<<NB, b256, 0, stream>>>(src, dst, histT, pairs, E, chunk, nbuck);
    bcount_k<<<nbuck, b256, 0, stream>>>(pairs, histT, cnt, dinv, ovf, N, nbuck, E);
    bfill_k<<<nbuck, b256, 0, stream>>>(pairs, histT, cnt, dinv, pr, ovf, N, nbuck, E);

    int ngroups = (N + 15) / 16;
    int gemm_blocks = (ngroups + 3) / 4;

    // layer 1: h = x @ W1 (fused f32->bf16 cast) ; buf16 = bf16(relu(agg(h)+b1))
    gemm_f32_k<<<gemm_blocks, b256, 0, stream>>>(x, W1, h, N);
    agg_k<<<2560, b256, 0, stream>>>((const uint4*)h, pr, b1, nullptr, buf16, N);
    // layer 2: h = buf16 @ W2 ; out = relu(agg(h) + b2)
    gemm_k<<<gemm_blocks, b256, 0, stream>>>((const u32*)buf16, W2, h, N);
    agg_k<<<2560, b256, 0, stream>>>((const uint4*)h, pr, b2, out, nullptr, N);
}

// Round 14
// 219.846 us; speedup vs baseline: 1.2178x; 1.0195x over previous
//
#include <hip/hip_runtime.h>

#define D 64
#define NB 256      // partition blocks for hist/scatter
#define BSHIFT 8    // bucket = 256 nodes
#define SLOTS 32    // fixed pr slots per node (31 payload + 1 chain/pad)
#define MAXCONT 65536

typedef unsigned int u32;
typedef unsigned short u16;
typedef short bf8v __attribute__((ext_vector_type(8)));
typedef float f4v __attribute__((ext_vector_type(4)));

__device__ __forceinline__ float bf_lo(u32 p) { return __uint_as_float(p << 16); }
__device__ __forceinline__ float bf_hi(u32 p) { return __uint_as_float(p & 0xffff0000u); }
__device__ __forceinline__ u32 bf_rne(float f) {
    u32 u = __float_as_uint(f);
    return (u + 0x7fffu + ((u >> 16) & 1u)) >> 16;
}

// ---------------- pass A: per-block bucket histogram (LDS atomics only) --------
__global__ __launch_bounds__(256) void hist_k(const int* __restrict__ dst,
                                              int* __restrict__ histT, int E, int chunk,
                                              int nbuck) {
    __shared__ int h[512];
    int t = threadIdx.x;
    for (int b = t; b < nbuck; b += 256) h[b] = 0;
    __syncthreads();
    int start = blockIdx.x * chunk;
    int endi = min(E, start + chunk);
    for (int j = start + t; j < endi; j += 256) atomicAdd(&h[dst[j] >> BSHIFT], 1);
    __syncthreads();
    for (int b = t; b < nbuck; b += 256) histT[b * NB + blockIdx.x] = h[b];
}

// ---------------- generic grid scan (for histT) ----------------
__global__ __launch_bounds__(1024) void gscan1_k(const int* __restrict__ in,
                                                 int* __restrict__ out,
                                                 int* __restrict__ partials, int M) {
    __shared__ int wsum[16];
    int t = threadIdx.x, wave = t >> 6, lane = t & 63;
    int i = blockIdx.x * 1024 + t;
    int v = (i < M) ? in[i] : 0;
    int x = v;
#pragma unroll
    for (int off = 1; off < 64; off <<= 1) {
        int y = __shfl_up(x, off, 64);
        if (lane >= off) x += y;
    }
    if (lane == 63) wsum[wave] = x;
    __syncthreads();
    if (wave == 0) {
        int s = (lane < 16) ? wsum[lane] : 0;
#pragma unroll
        for (int off = 1; off < 16; off <<= 1) {
            int y = __shfl_up(s, off, 64);
            if (lane >= off) s += y;
        }
        if (lane < 16) wsum[lane] = s;
    }
    __syncthreads();
    int woff = (wave > 0) ? wsum[wave - 1] : 0;
    if (i < M) out[i] = x + woff - v;
    if (t == 0) partials[blockIdx.x] = wsum[15];
}

__global__ __launch_bounds__(128) void scan2_k(const int* __restrict__ partials,
                                               int* __restrict__ blockoff,
                                               int* __restrict__ totalp, int nb) {
    __shared__ int s[128];
    int t = threadIdx.x;
    int v = (t < nb) ? partials[t] : 0;
    s[t] = v;
    __syncthreads();
    for (int off = 1; off < 128; off <<= 1) {
        int add = (t >= off) ? s[t - off] : 0;
        __syncthreads();
        s[t] += add;
        __syncthreads();
    }
    blockoff[t] = s[t] - v;
    if (t == nb - 1) *totalp = s[t];
}

// seg(x) = histT[x] + blockoff2[x>>10]  (gadd fused into all segT readers)
__device__ __forceinline__ int seg_at(const int* __restrict__ histT,
                                      const int* __restrict__ blockoff2, int x) {
    return histT[x] + blockoff2[x >> 10];
}

// ---------------- pass B: scatter edges into bucket-sorted segments ----------
__global__ __launch_bounds__(256) void bscat_k(const int* __restrict__ src,
                                               const int* __restrict__ dst,
                                               const int* __restrict__ histT,
                                               const int* __restrict__ blockoff2,
                                               int2* __restrict__ pairs, int E, int chunk,
                                               int nbuck) {
    __shared__ int sbase[512];
    __shared__ int rank[512];
    int t = threadIdx.x;
    for (int b = t; b < nbuck; b += 256) {
        sbase[b] = seg_at(histT, blockoff2, b * NB + blockIdx.x);
        rank[b] = 0;
    }
    __syncthreads();
    int start = blockIdx.x * chunk;
    int endi = min(E, start + chunk);
    for (int j = start + t; j < endi; j += 256) {
        int d = dst[j];
        int b = d >> BSHIFT;
        int pos = sbase[b] + atomicAdd(&rank[b], 1);
        pairs[pos] = make_int2(src[j], d);
    }
}

// ---------------- pass C1: per-node count (LDS) -> cnt + dinv; zero ovf -------
__global__ __launch_bounds__(256) void bcount_k(const int2* __restrict__ pairs,
                                                const int* __restrict__ histT,
                                                const int* __restrict__ blockoff2,
                                                int* __restrict__ cnt,
                                                float* __restrict__ dinv,
                                                int* __restrict__ ovf, int N, int nbuck,
                                                int E) {
    __shared__ int c[1 << BSHIFT];
    int t = threadIdx.x;
    int b = blockIdx.x;
    int base = b << BSHIFT;
    if (b == 0 && t == 0) *ovf = 0;
    c[t] = 0;
    __syncthreads();
    int s0 = seg_at(histT, blockoff2, b * NB);
    int s1 = (b + 1 < nbuck) ? seg_at(histT, blockoff2, (b + 1) * NB) : E;
    for (int j = s0 + t; j < s1; j += 256) atomicAdd(&c[pairs[j].y - base], 1);
    __syncthreads();
    int n = base + t;
    if (n < N) {
        cnt[n] = c[t];
        dinv[n] = rsqrtf((float)c[t] + 1.0f);
    }
}

// ---------------- pass C2: per-bucket fixed-32 fill with overflow chains ------
// node n's slots: pr[32n .. 32n+31]; slot 0 = self, 1..30 = edges/pads,
// slot 31 = pad (n,+0.0) or chain (cont_idx, -0.0). Cont blocks at pr+32N.
__global__ __launch_bounds__(256) void bfill_k(const int2* __restrict__ pairs,
                                               const int* __restrict__ histT,
                                               const int* __restrict__ blockoff2,
                                               const int* __restrict__ cnt,
                                               const float* __restrict__ dinv,
                                               int2* __restrict__ pr, int* __restrict__ ovf,
                                               int N, int nbuck, int E) {
    __shared__ int cur[1 << BSHIFT];
    __shared__ int cbase[1 << BSHIFT];
    int t = threadIdx.x;
    int b = blockIdx.x;
    int base = b << BSHIFT;
    int n = base + t;
    int nblk = 0;
    if (n < N) {
        int c = cnt[n];
        float di = dinv[n];
        pr[(size_t)n * SLOTS] = make_int2(n, __float_as_int(di * di));  // self
        nblk = (c > 30) ? (c / 31) : 0;
        int cb = 0;
        if (nblk) cb = atomicAdd(ovf, nblk);
        cbase[t] = cb;
        cur[t] = 1;
        if (nblk == 0) {
            pr[(size_t)n * SLOTS + 31] = make_int2(n, 0);  // +0.0 pad
        } else {
            pr[(size_t)n * SLOTS + 31] = make_int2(cb, (int)0x80000000u);  // chain
            for (int k = 0; k < nblk; ++k) {
                size_t cs = (size_t)N * SLOTS + (size_t)(cb + k) * SLOTS + 31;
                pr[cs] = (k < nblk - 1) ? make_int2(cb + k + 1, (int)0x80000000u)
                                        : make_int2(n, 0);
            }
        }
    }
    __syncthreads();
    int s0 = seg_at(histT, blockoff2, b * NB);
    int s1 = (b + 1 < nbuck) ? seg_at(histT, blockoff2, (b + 1) * NB) : E;
    for (int j = s0 + t; j < s1; j += 256) {
        int2 e = pairs[j];
        int local = e.y - base;
        int pos = atomicAdd(&cur[local], 1);
        size_t phys;
        if (pos < 31)
            phys = (size_t)e.y * SLOTS + pos;
        else
            phys = (size_t)N * SLOTS +
                   (size_t)(cbase[local] + (pos - 31) / 31) * SLOTS + (pos - 31) % 31;
        pr[phys] = make_int2(e.x, __float_as_int(dinv[e.x] * dinv[e.y]));
    }
    __syncthreads();
    if (n < N) {
        int total = 31 + 31 * nblk;
        int cb = cbase[t];
        for (int pos = cur[t]; pos < total; ++pos) {
            size_t phys;
            if (pos < 31)
                phys = (size_t)n * SLOTS + pos;
            else
                phys = (size_t)N * SLOTS + (size_t)(cb + (pos - 31) / 31) * SLOTS +
                       (pos - 31) % 31;
            pr[phys] = make_int2(n, 0);  // +0.0 pad
        }
    }
}

// ---------------- dense GEMM via MFMA 16x16x32 bf16: hout = in @ W ------------

__device__ __forceinline__ void gemm_body(bf8v Af0, bf8v Af1, const bf8v Bf[2][4],
                                          u16* __restrict__ hout, int base, int m,
                                          int quad, int N) {
    f4v acc[4] = {{0.f, 0.f, 0.f, 0.f},
                  {0.f, 0.f, 0.f, 0.f},
                  {0.f, 0.f, 0.f, 0.f},
                  {0.f, 0.f, 0.f, 0.f}};
#pragma unroll
    for (int nb = 0; nb < 4; ++nb)
        acc[nb] = __builtin_amdgcn_mfma_f32_16x16x32_bf16(Af0, Bf[0][nb], acc[nb], 0, 0, 0);
#pragma unroll
    for (int nb = 0; nb < 4; ++nb)
        acc[nb] = __builtin_amdgcn_mfma_f32_16x16x32_bf16(Af1, Bf[1][nb], acc[nb], 0, 0, 0);
#pragma unroll
    for (int nb = 0; nb < 4; ++nb)
#pragma unroll
        for (int r = 0; r < 4; ++r) {
            int rowi = base + quad * 4 + r;
            if (rowi < N) hout[(size_t)rowi * D + nb * 16 + m] = (u16)bf_rne(acc[nb][r]);
        }
}

__device__ __forceinline__ void load_B(const float* __restrict__ W, bf8v Bf[2][4], int m,
                                       int quad) {
#pragma unroll
    for (int kc = 0; kc < 2; ++kc)
#pragma unroll
        for (int nb = 0; nb < 4; ++nb)
#pragma unroll
            for (int j = 0; j < 8; ++j)
                Bf[kc][nb][j] = (short)bf_rne(W[(32 * kc + 8 * quad + j) * D + m + 16 * nb]);
}

__global__ __launch_bounds__(256) void gemm_k(const u32* __restrict__ hb,
                                              const float* __restrict__ W,
                                              u16* __restrict__ hout, int N) {
    int t = threadIdx.x;
    int lane = t & 63;
    int m = lane & 15;
    int quad = lane >> 4;
    bf8v Bf[2][4];
    load_B(W, Bf, m, quad);
    int ngroups = (N + 15) >> 4;
    int g = blockIdx.x * 4 + (t >> 6);
    int stride = gridDim.x * 4;
    for (; g < ngroups; g += stride) {
        int base = g * 16;
        int r0 = base + m;
        if (r0 >= N) r0 = N - 1;
        bf8v Af0 = *(const bf8v*)(hb + (size_t)r0 * 32 + quad * 4);
        bf8v Af1 = *(const bf8v*)(hb + (size_t)r0 * 32 + 16 + quad * 4);
        gemm_body(Af0, Af1, Bf, hout, base, m, quad, N);
    }
}

__global__ __launch_bounds__(256) void gemm_f32_k(const float* __restrict__ xf,
                                                  const float* __restrict__ W,
                                                  u16* __restrict__ hout, int N) {
    int t = threadIdx.x;
    int lane = t & 63;
    int m = lane & 15;
    int quad = lane >> 4;
    bf8v Bf[2][4];
    load_B(W, Bf, m, quad);
    int ngroups = (N + 15) >> 4;
    int g = blockIdx.x * 4 + (t >> 6);
    int stride = gridDim.x * 4;
    for (; g < ngroups; g += stride) {
        int base = g * 16;
        int r0 = base + m;
        if (r0 >= N) r0 = N - 1;
        const float* rp = xf + (size_t)r0 * D;
        float4 a0 = *(const float4*)(rp + quad * 8);
        float4 a1 = *(const float4*)(rp + quad * 8 + 4);
        float4 a2 = *(const float4*)(rp + 32 + quad * 8);
        float4 a3 = *(const float4*)(rp + 32 + quad * 8 + 4);
        bf8v Af0, Af1;
        Af0[0] = (short)bf_rne(a0.x); Af0[1] = (short)bf_rne(a0.y);
        Af0[2] = (short)bf_rne(a0.z); Af0[3] = (short)bf_rne(a0.w);
        Af0[4] = (short)bf_rne(a1.x); Af0[5] = (short)bf_rne(a1.y);
        Af0[6] = (short)bf_rne(a1.z); Af0[7] = (short)bf_rne(a1.w);
        Af1[0] = (short)bf_rne(a2.x); Af1[1] = (short)bf_rne(a2.y);
        Af1[2] = (short)bf_rne(a2.z); Af1[3] = (short)bf_rne(a2.w);
        Af1[4] = (short)bf_rne(a3.x); Af1[5] = (short)bf_rne(a3.y);
        Af1[6] = (short)bf_rne(a3.z); Af1[7] = (short)bf_rne(a3.w);
        gemm_body(Af0, Af1, Bf, hout, base, m, quad, N);
    }
}

// NOTE: parameter renamed gt/wt — a param named `w` would macro-substitute
// into the member access `.w` (R13 compile failure).
#define FMA4(gt, wt)                                                            \
    v0 = fmaf(bf_lo((gt).x), (wt), v0); v1 = fmaf(bf_hi((gt).x), (wt), v1);     \
    v2 = fmaf(bf_lo((gt).y), (wt), v2); v3 = fmaf(bf_hi((gt).y), (wt), v3);     \
    v4 = fmaf(bf_lo((gt).z), (wt), v4); v5 = fmaf(bf_hi((gt).z), (wt), v5);     \
    v6 = fmaf(bf_lo((gt).w), (wt), v6); v7 = fmaf(bf_hi((gt).w), (wt), v7);

// ---------------- lean gather: out = relu( A_norm @ h + b ) ----------------
// wave per node, fixed 32 slots at pr[32i]. 8 lanes per gathered row:
// q = lane>>3 handles slots {2q,2q+1,16+2q,16+2q+1}; p = lane&7 picks 8 packed
// bf16 features (uint4). Cross-iteration prefetch of the NEXT node's pr quads
// hides the pr->gather serialization (steady state: one gather round-trip per
// node). Natural VGPR allocation (=64) is the measured optimum (R6/R11).
__global__ __launch_bounds__(256) void agg_k(const uint4* __restrict__ h4,
                                             const int2* __restrict__ pr,
                                             const float* __restrict__ b,
                                             float* __restrict__ out_f32,
                                             u16* __restrict__ out_b16, int N) {
    int t = threadIdx.x;
    int lane = t & 63;
    int p = lane & 7;
    int q = lane >> 3;
    float4 ba = *(const float4*)(b + 8 * p);
    float4 bb = *(const float4*)(b + 8 * p + 4);
    int wid = blockIdx.x * 4 + (t >> 6);
    int nw = gridDim.x * 4;
    if (wid >= N) return;
    const int4* bp0 = (const int4*)(pr + (size_t)wid * SLOTS);
    int4 pel0 = bp0[q];
    int4 pel1 = bp0[8 + q];
    for (int i = wid; i < N; i += nw) {
        int4 el0 = pel0;
        int4 el1 = pel1;
        // issue current node's gathers
        uint4 g0 = h4[(size_t)(u32)el0.x * 8 + p];
        uint4 g1 = h4[(size_t)(u32)el0.z * 8 + p];
        uint4 g2 = h4[(size_t)(u32)el1.x * 8 + p];
        uint4 g3 = h4[(size_t)(u32)el1.z * 8 + p];
        // prefetch next node's pr quads (latency hidden under this node's work)
        {
            int j = i + nw;
            int jc = (j < N) ? j : i;
            const int4* bpn = (const int4*)(pr + (size_t)jc * SLOTS);
            pel0 = bpn[q];
            pel1 = bpn[8 + q];
        }
        float v0 = 0.f, v1 = 0.f, v2 = 0.f, v3 = 0.f;
        float v4 = 0.f, v5 = 0.f, v6 = 0.f, v7 = 0.f;
        FMA4(g0, __int_as_float(el0.y));
        FMA4(g1, __int_as_float(el0.w));
        FMA4(g2, __int_as_float(el1.y));
        FMA4(g3, __int_as_float(el1.w));
        // rare chain path (deg > 30): wave-uniform
        int flag = __shfl(el1.w, 63, 64);
        while (flag < 0) {
            int c = __shfl(el1.z, 63, 64);
            const int4* bpc = (const int4*)(pr + (size_t)N * SLOTS + (size_t)c * SLOTS);
            el0 = bpc[q];
            el1 = bpc[8 + q];
            g0 = h4[(size_t)(u32)el0.x * 8 + p];
            g1 = h4[(size_t)(u32)el0.z * 8 + p];
            g2 = h4[(size_t)(u32)el1.x * 8 + p];
            g3 = h4[(size_t)(u32)el1.z * 8 + p];
            FMA4(g0, __int_as_float(el0.y));
            FMA4(g1, __int_as_float(el0.w));
            FMA4(g2, __int_as_float(el1.y));
            FMA4(g3, __int_as_float(el1.w));
            flag = __shfl(el1.w, 63, 64);
        }
        v0 += __shfl_xor(v0, 8, 64);  v1 += __shfl_xor(v1, 8, 64);
        v2 += __shfl_xor(v2, 8, 64);  v3 += __shfl_xor(v3, 8, 64);
        v4 += __shfl_xor(v4, 8, 64);  v5 += __shfl_xor(v5, 8, 64);
        v6 += __shfl_xor(v6, 8, 64);  v7 += __shfl_xor(v7, 8, 64);
        v0 += __shfl_xor(v0, 16, 64); v1 += __shfl_xor(v1, 16, 64);
        v2 += __shfl_xor(v2, 16, 64); v3 += __shfl_xor(v3, 16, 64);
        v4 += __shfl_xor(v4, 16, 64); v5 += __shfl_xor(v5, 16, 64);
        v6 += __shfl_xor(v6, 16, 64); v7 += __shfl_xor(v7, 16, 64);
        v0 += __shfl_xor(v0, 32, 64); v1 += __shfl_xor(v1, 32, 64);
        v2 += __shfl_xor(v2, 32, 64); v3 += __shfl_xor(v3, 32, 64);
        v4 += __shfl_xor(v4, 32, 64); v5 += __shfl_xor(v5, 32, 64);
        v6 += __shfl_xor(v6, 32, 64); v7 += __shfl_xor(v7, 32, 64);
        v0 = fmaxf(v0 + ba.x, 0.f); v1 = fmaxf(v1 + ba.y, 0.f);
        v2 = fmaxf(v2 + ba.z, 0.f); v3 = fmaxf(v3 + ba.w, 0.f);
        v4 = fmaxf(v4 + bb.x, 0.f); v5 = fmaxf(v5 + bb.y, 0.f);
        v6 = fmaxf(v6 + bb.z, 0.f); v7 = fmaxf(v7 + bb.w, 0.f);
        if (q == 0) {
            if (out_b16) {
                uint4 o;
                o.x = bf_rne(v0) | (bf_rne(v1) << 16);
                o.y = bf_rne(v2) | (bf_rne(v3) << 16);
                o.z = bf_rne(v4) | (bf_rne(v5) << 16);
                o.w = bf_rne(v6) | (bf_rne(v7) << 16);
                *(uint4*)(out_b16 + (size_t)i * D + 8 * p) = o;
            } else {
                float* dst = out_f32 + (size_t)i * D + 8 * p;
                *(float4*)dst = make_float4(v0, v1, v2, v3);
                *(float4*)(dst + 4) = make_float4(v4, v5, v6, v7);
            }
        }
    }
}

// ---------------- launch ----------------

extern "C" void kernel_launch(void* const* d_in, const int* in_sizes, int n_in,
                              void* d_out, int out_size, void* d_ws, size_t ws_size,
                              hipStream_t stream) {
    const float* x  = (const float*)d_in[0];
    const int*   ei = (const int*)d_in[1];
    const float* W1 = (const float*)d_in[2];
    const float* b1 = (const float*)d_in[3];
    const float* W2 = (const float*)d_in[4];
    const float* b2 = (const float*)d_in[5];
    float* out = (float*)d_out;

    int N = in_sizes[0] / D;
    int E = in_sizes[1] / 2;
    const int* src = ei;
    const int* dst = ei + E;

    int nbuck = (N + (1 << BSHIFT) - 1) >> BSHIFT;  // 391
    int chunk = (E + NB - 1) / NB;
    int M = nbuck * NB;

    char* ws = (char*)d_ws;
    size_t off = 0;
    auto align256 = [](size_t v) { return (v + 255) & ~(size_t)255; };
    int* cnt = (int*)(ws + off);       off += align256((size_t)N * 4);
    float* dinv = (float*)(ws + off);  off += align256((size_t)N * 4);
    int* partials2 = (int*)(ws + off); off += 512;
    int* blockoff2 = (int*)(ws + off); off += 512;
    int* scratch = (int*)(ws + off);   off += 256;
    int* ovf = (int*)(ws + off);       off += 256;
    int* histT = (int*)(ws + off);     off += align256((size_t)M * 4);
    int2* pairs = (int2*)(ws + off);   off += align256((size_t)E * 8);
    int2* pr = (int2*)(ws + off);      off += align256(((size_t)N + MAXCONT) * SLOTS * 8);
    u16* h = (u16*)(ws + off);         off += align256((size_t)N * D * 2);
    u16* buf16 = (u16*)(ws + off);     off += align256((size_t)N * D * 2);

    dim3 b256(256);
    int nbG = (M + 1023) / 1024;  // hist-scan blocks (98)

    hist_k<<<NB, b256, 0, stream>>>(dst, histT, E, chunk, nbuck);
    gscan1_k<<<nbG, 1024, 0, stream>>>(histT, histT, partials2, M);
    scan2_k<<<1, 128, 0, stream>>>(partials2, blockoff2, scratch, nbG);
    bscat_k<<<NB, b256, 0, stream>>>(src, dst, histT, blockoff2, pairs, E, chunk, nbuck);
    bcount_k<<<nbuck, b256, 0, stream>>>(pairs, histT, blockoff2, cnt, dinv, ovf, N, nbuck,
                                         E);
    bfill_k<<<nbuck, b256, 0, stream>>>(pairs, histT, blockoff2, cnt, dinv, pr, ovf, N,
                                        nbuck, E);

    int ngroups = (N + 15) / 16;
    int gemm_blocks = (ngroups + 3) / 4;

    // layer 1: h = x @ W1 (fused f32->bf16 cast) ; buf16 = bf16(relu(agg(h)+b1))
    gemm_f32_k<<<gemm_blocks, b256, 0, stream>>>(x, W1, h, N);
    agg_k<<<2560, b256, 0, stream>>>((const uint4*)h, pr, b1, nullptr, buf16, N);
    // layer 2: h = buf16 @ W2 ; out = relu(agg(h) + b2)
    gemm_k<<<gemm_blocks, b256, 0, stream>>>((const u32*)buf16, W2, h, N);
    agg_k<<<2560, b256, 0, stream>>>((const uint4*)h, pr, b2, out, nullptr, N);
}